// Round 16
// baseline (253.282 us; speedup 1.0000x reference)
//
#include <hip/hip_runtime.h>

using f16   = _Float16;
using f16x4 = __attribute__((ext_vector_type(4))) _Float16;
using f16x8 = __attribute__((ext_vector_type(8))) _Float16;
using f32x4 = __attribute__((ext_vector_type(4))) float;

#define DEVI __device__ __forceinline__

namespace {
// 64KB LDS, 512-thread blocks (8 waves = 4 heads x 2 seq-halves):
//  S_XQ @0   : Xq [64][128] f16 swzA -> P (2KB/wave chunks) -> O [64][128]
//  S_XK @16K : Xk [64][128] f16 swzA -> Xv (regs->LDS after BAR2)
//  S_SCR @32K: 8KB per head: Q [64][32] @0 | K [64][32] @4K (-> V^T [32][64])
constexpr int S_XQ  = 0;
constexpr int S_XK  = 16384;
constexpr int S_SCR = 32768;
constexpr float LOGIT_MAX_C = 4.6051701859880914f;  // log(100)
constexpr float L2E = 1.4426950408889634f;
}

// XOR swizzles. Masks only touch bits >=4 so 8/16B-aligned vector accesses stay
// block-aligned with byte order preserved (bit-3 masks corrupt — R8 lesson).
DEVI int swzA(int row, int b) { return (row << 8) + (b ^ ((row & 7) << 4)); }   // 256B rows
DEVI int swz64(int row, int b) { return (row << 6) + (b ^ (((row >> 1) & 3) << 4)); }  // 64B rows

DEVI f16x8 ldA(const char* base, int row, int k0) {   // [*,128] f16 tile, b128
  return *reinterpret_cast<const f16x8*>(base + swzA(row, k0 << 1));
}

// Stage one 64x128 fp32 tile -> f16 swizzled LDS tile (512 threads, 4 f4 each)
DEVI void stage_in(const float* __restrict__ src, char* __restrict__ dst, int tid) {
#pragma unroll
  for (int i = 0; i < 4; ++i) {
    int f = tid + (i << 9);
    float4 v = reinterpret_cast<const float4*>(src)[f];
    f16x4 h;
    h[0] = (f16)v.x; h[1] = (f16)v.y; h[2] = (f16)v.z; h[3] = (f16)v.w;
    *reinterpret_cast<f16x4*>(dst + swzA(f >> 5, (f & 31) << 3)) = h;
  }
}

// Half-seq projection: out[hf rows 32][head-w cols 32] = X @ W^T. 16 MFMA.
DEVI void proj_split(const char* __restrict__ xb, const f16* __restrict__ Wm,
                     f32x4 (&acc)[2][2], int w, int hf, int lr, int lg) {
#pragma unroll
  for (int mtl = 0; mtl < 2; ++mtl)
#pragma unroll
    for (int n = 0; n < 2; ++n)
      acc[mtl][n] = f32x4{0.f, 0.f, 0.f, 0.f};
#pragma unroll
  for (int kt = 0; kt < 4; ++kt) {
    f16x8 b0 = *reinterpret_cast<const f16x8*>(Wm + (w * 32 + lr) * 128 + kt * 32 + lg * 8);
    f16x8 b1 = *reinterpret_cast<const f16x8*>(Wm + (w * 32 + 16 + lr) * 128 + kt * 32 + lg * 8);
#pragma unroll
    for (int mtl = 0; mtl < 2; ++mtl) {
      f16x8 a = ldA(xb, hf * 32 + mtl * 16 + lr, kt * 32 + lg * 8);
      acc[mtl][0] = __builtin_amdgcn_mfma_f32_16x16x32_f16(a, b0, acc[mtl][0], 0, 0, 0);
      acc[mtl][1] = __builtin_amdgcn_mfma_f32_16x16x32_f16(a, b1, acc[mtl][1], 0, 0, 0);
    }
  }
}

// C/D -> [64 rows][32 cols] f16 scratch (64B rows, swz64), own half rows.
DEVI void epi_half(const f32x4 (&acc)[2][2], char* __restrict__ scr,
                   const float* __restrict__ bias, int hf, int lr, int lg) {
  float b0 = bias ? bias[lr] : 0.f;
  float b1 = bias ? bias[16 + lr] : 0.f;
#pragma unroll
  for (int mtl = 0; mtl < 2; ++mtl)
#pragma unroll
    for (int n = 0; n < 2; ++n)
#pragma unroll
      for (int r = 0; r < 4; ++r) {
        int row = hf * 32 + mtl * 16 + lg * 4 + r;
        *reinterpret_cast<f16*>(scr + swz64(row, (n * 16 + lr) << 1)) =
            (f16)(acc[mtl][n][r] + (n ? b1 : b0));
      }
}
DEVI f16x8 ldS64(const char* __restrict__ scr, int row, int lg) {
  return *reinterpret_cast<const f16x8*>(scr + swz64(row, lg << 4));
}

// fp32 weights -> f16 workspace (Wq,Wk,Wv,Wp)
__global__ void wcvt_kernel(const float* __restrict__ Wq, const float* __restrict__ Wk,
                            const float* __restrict__ Wv, const float* __restrict__ Wp,
                            f16* __restrict__ W16) {
  int idx = blockIdx.x * 256 + threadIdx.x;   // 0..16383
  int m = idx >> 12;
  int off = (idx & 4095) << 2;
  const float* src = m == 0 ? Wq : m == 1 ? Wk : m == 2 ? Wv : Wp;
  float4 v = *reinterpret_cast<const float4*>(src + off);
  f16x4 h;
  h[0] = (f16)v.x; h[1] = (f16)v.y; h[2] = (f16)v.z; h[3] = (f16)v.w;
  *reinterpret_cast<f16x4*>(W16 + (m << 14) + off) = h;
}

__global__ __launch_bounds__(512, 4)
void fpca_kernel(const float* __restrict__ q_in, const float* __restrict__ k_in,
                 const float* __restrict__ v_in, const float* __restrict__ pos_in,
                 const f16* __restrict__ W16,
                 const float* __restrict__ bq, const float* __restrict__ bv,
                 const float* __restrict__ bp, const float* __restrict__ lsc,
                 float* __restrict__ d_x, float* __restrict__ d_attn) {
  __shared__ char smem[65536];
  const int tid = threadIdx.x;
  const int W = tid >> 6;        // wave id: head w = W&3, seq-half hf = W>>2
  const int w = W & 3;
  const int hf = W >> 2;
  const int lane = tid & 63;
  const int lr = lane & 15;
  const int lg = lane >> 4;
  const int win = blockIdx.x;
  const int b = win >> 8;
  const size_t winOff = (size_t)win << 13;
  const f16* Wq16 = W16;
  const f16* Wk16 = W16 + 16384;
  const f16* Wv16 = W16 + 32768;
  const f16* Wp16 = W16 + 49152;
  char* Qscr = smem + S_SCR + (w << 13);   // head-w Q scratch (4KB)
  char* Kscr = Qscr + 4096;                // head-w K scratch -> V^T
  char* Pscr = smem + S_XQ + (W << 11);    // 2KB wave-private P chunk

  // ---- ph0: stage Xq, Xk; prefetch Xv into f16 regs ----
  stage_in(q_in + winOff, smem + S_XQ, tid);
  stage_in(k_in + winOff, smem + S_XK, tid);
  const float4* vsrc = reinterpret_cast<const float4*>(v_in + winOff);
  f16x4 pfh[4];
#pragma unroll
  for (int i = 0; i < 4; ++i) {
    float4 v = vsrc[tid + (i << 9)];
    pfh[i][0] = (f16)v.x; pfh[i][1] = (f16)v.y;
    pfh[i][2] = (f16)v.z; pfh[i][3] = (f16)v.w;
  }
  __syncthreads();  // BAR1: stage regions valid

  // ---- Q proj (own half rows) -> Qscr -> bQ (own rows); K proj -> Kscr ----
  f32x4 acc[2][2];
  proj_split(smem + S_XQ, Wq16, acc, w, hf, lr, lg);
  epi_half(acc, Qscr, bq + w * 32, hf, lr, lg);
  f16x8 bQ[2];
#pragma unroll
  for (int ntl = 0; ntl < 2; ++ntl)
    bQ[ntl] = ldS64(Qscr, hf * 32 + ntl * 16 + lr, lg);

  proj_split(smem + S_XK, Wk16, acc, w, hf, lr, lg);
  epi_half(acc, Kscr, nullptr, hf, lr, lg);
  __syncthreads();  // BAR2: K complete (both halves); all stage reads done

  // ---- Xv regs -> S_XK; aK hoist (both halves' K rows) ----
#pragma unroll
  for (int i = 0; i < 4; ++i) {
    int f = tid + (i << 9);
    *reinterpret_cast<f16x4*>(smem + S_XK + swzA(f >> 5, (f & 31) << 3)) = pfh[i];
  }
  f16x8 aK[4];
#pragma unroll
  for (int mt = 0; mt < 4; ++mt) aK[mt] = ldS64(Kscr, mt * 16 + lr, lg);

  // ---- S^T = K Q^T (own q half) + scale/pos, softmax, attn out, P16 ----
  const float scale = exp2f(fminf(lsc[w], LOGIT_MAX_C) * L2E);
  const float* pos = pos_in + (((size_t)b * 4 + w) << 12);
  float* attn_out = d_attn + (((size_t)win * 4 + w) << 12);
  f16x4 P16[4][2];   // P16[mt][ntl]: q = hf*32+ntl*16+lr, k = mt*16+lg*4+r
#pragma unroll
  for (int ntl = 0; ntl < 2; ++ntl) {
    f32x4 s[4];
#pragma unroll
    for (int mt = 0; mt < 4; ++mt) s[mt] = f32x4{0.f, 0.f, 0.f, 0.f};
#pragma unroll
    for (int mt = 0; mt < 4; ++mt)
      s[mt] = __builtin_amdgcn_mfma_f32_16x16x32_f16(aK[mt], bQ[ntl], s[mt], 0, 0, 0);
    const int q = hf * 32 + ntl * 16 + lr;
#pragma unroll
    for (int mt = 0; mt < 4; ++mt) {
      float4 pv = *reinterpret_cast<const float4*>(pos + (q << 6) + mt * 16 + lg * 4);
      s[mt][0] = s[mt][0] * scale + pv.x;
      s[mt][1] = s[mt][1] * scale + pv.y;
      s[mt][2] = s[mt][2] * scale + pv.z;
      s[mt][3] = s[mt][3] * scale + pv.w;
    }
    float m = s[0][0];
#pragma unroll
    for (int mt = 0; mt < 4; ++mt)
#pragma unroll
      for (int r = 0; r < 4; ++r) m = fmaxf(m, s[mt][r]);
    m = fmaxf(m, __shfl_xor(m, 16));
    m = fmaxf(m, __shfl_xor(m, 32));
    float sum = 0.f;
#pragma unroll
    for (int mt = 0; mt < 4; ++mt)
#pragma unroll
      for (int r = 0; r < 4; ++r) {
        float e = exp2f((s[mt][r] - m) * L2E);
        s[mt][r] = e;
        sum += e;
      }
    sum += __shfl_xor(sum, 16);
    sum += __shfl_xor(sum, 32);
    float rinv = __builtin_amdgcn_rcpf(sum);
#pragma unroll
    for (int mt = 0; mt < 4; ++mt) {
      float4 o;
      o.x = (s[mt][0] *= rinv);
      o.y = (s[mt][1] *= rinv);
      o.z = (s[mt][2] *= rinv);
      o.w = (s[mt][3] *= rinv);
      *reinterpret_cast<float4*>(attn_out + (q << 6) + mt * 16 + lg * 4) = o;
      P16[mt][ntl][0] = (f16)s[mt][0];
      P16[mt][ntl][1] = (f16)s[mt][1];
      P16[mt][ntl][2] = (f16)s[mt][2];
      P16[mt][ntl][3] = (f16)s[mt][3];
    }
  }

  // ---- P k-halves -> Pscr [32 q][32 k] (time-shared; S_XQ free post-BAR2) ----
#define WR_P(MT)                                                                   \
  {                                                                                \
    _Pragma("unroll") for (int ntl = 0; ntl < 2; ++ntl) {                          \
      const int row = ntl * 16 + lr;                                               \
      *reinterpret_cast<f16x4*>(Pscr + (row << 6) +                                \
          (((((MT) & 1) << 5) + (lg << 3)) ^ (((row >> 1) & 3) << 4))) =           \
          P16[MT][ntl];                                                            \
    }                                                                              \
  }
  f16x8 aP[2][2];   // aP[qt][h]
#pragma unroll
  for (int h = 0; h < 2; ++h) {
    WR_P(2 * h)
    WR_P(2 * h + 1)
#pragma unroll
    for (int qt = 0; qt < 2; ++qt) {
      const int row = qt * 16 + lr;
      aP[qt][h] = *reinterpret_cast<const f16x8*>(Pscr + (row << 6) +
          ((lg << 4) ^ (((row >> 1) & 3) << 4)));
    }
  }
#undef WR_P
  __syncthreads();  // BAR3: Xv staged (all); all aK hoists done

  // ---- V proj (own seq half) -> V^T into Kscr (K dead) ----
  proj_split(smem + S_XK, Wv16, acc, w, hf, lr, lg);
  {
    float c0 = bv[w * 32 + lr], c1 = bv[w * 32 + 16 + lr];
#pragma unroll
    for (int mtl = 0; mtl < 2; ++mtl)
#pragma unroll
      for (int n = 0; n < 2; ++n) {
        int d = n * 16 + lr;                 // local feature row of V^T [32][64]
        f16x4 h;
        h[0] = (f16)(acc[mtl][n][0] + (n ? c1 : c0));
        h[1] = (f16)(acc[mtl][n][1] + (n ? c1 : c0));
        h[2] = (f16)(acc[mtl][n][2] + (n ? c1 : c0));
        h[3] = (f16)(acc[mtl][n][3] + (n ? c1 : c0));
        *reinterpret_cast<f16x4*>(Kscr + (d << 7) +
            ((hf * 64 + mtl * 32 + lg * 8) ^ ((d & 7) << 4))) = h;
      }
  }
  __syncthreads();  // BAR4: V^T complete (both halves)

  // ---- bV hoist; O_h(own q rows) = P @ V_h (8 MFMA) ----
  f16x8 bV[2][2];
#pragma unroll
  for (int n = 0; n < 2; ++n)
#pragma unroll
    for (int kt = 0; kt < 2; ++kt) {
      int d = n * 16 + lr;
      bV[n][kt] = *reinterpret_cast<const f16x8*>(Kscr + (d << 7) +
          ((kt * 64 + lg * 16) ^ ((d & 7) << 4)));
    }
  f32x4 oacc[2][2];
#pragma unroll
  for (int qt = 0; qt < 2; ++qt)
#pragma unroll
    for (int n = 0; n < 2; ++n)
      oacc[qt][n] = f32x4{0.f, 0.f, 0.f, 0.f};
#pragma unroll
  for (int qt = 0; qt < 2; ++qt)
#pragma unroll
    for (int kt = 0; kt < 2; ++kt) {
      oacc[qt][0] = __builtin_amdgcn_mfma_f32_16x16x32_f16(aP[qt][kt], bV[0][kt], oacc[qt][0], 0, 0, 0);
      oacc[qt][1] = __builtin_amdgcn_mfma_f32_16x16x32_f16(aP[qt][kt], bV[1][kt], oacc[qt][1], 0, 0, 0);
    }

  // ---- O (own rows, head cols) -> S_XQ row-major (over P; aP all hoisted) ----
#pragma unroll
  for (int qt = 0; qt < 2; ++qt)
#pragma unroll
    for (int n = 0; n < 2; ++n)
#pragma unroll
      for (int r = 0; r < 4; ++r) {
        int row = hf * 32 + qt * 16 + lg * 4 + r;
        int col = w * 32 + n * 16 + lr;
        *reinterpret_cast<f16*>(smem + S_XQ + swzA(row, col << 1)) = (f16)oacc[qt][n][r];
      }
  __syncthreads();  // BAR5: O complete

  // ---- x (own rows, head-w cols) = O @ Wp^T + bp -> global fp32 ----
  f32x4 xacc[2][2];
  proj_split(smem + S_XQ, Wp16, xacc, w, hf, lr, lg);
  const float b0 = bp[w * 32 + lr];
  const float b1 = bp[w * 32 + 16 + lr];
  float* xo = d_x + winOff;
#pragma unroll
  for (int mtl = 0; mtl < 2; ++mtl)
#pragma unroll
    for (int n = 0; n < 2; ++n)
#pragma unroll
      for (int r = 0; r < 4; ++r) {
        int row = hf * 32 + mtl * 16 + lg * 4 + r;
        int col = w * 32 + n * 16 + lr;
        xo[(row << 7) + col] = xacc[mtl][n][r] + (n ? b1 : b0);
      }
}

extern "C" void kernel_launch(void* const* d_in, const int* in_sizes, int n_in,
                              void* d_out, int out_size, void* d_ws, size_t ws_size,
                              hipStream_t stream) {
  const float* q   = (const float*)d_in[0];
  const float* k   = (const float*)d_in[1];
  const float* v   = (const float*)d_in[2];
  const float* pos = (const float*)d_in[3];
  const float* Wq  = (const float*)d_in[4];
  const float* bq  = (const float*)d_in[5];
  const float* Wk  = (const float*)d_in[6];
  const float* Wv  = (const float*)d_in[7];
  const float* bv  = (const float*)d_in[8];
  const float* Wp  = (const float*)d_in[9];
  const float* bp  = (const float*)d_in[10];
  const float* ls  = (const float*)d_in[11];
  f16* W16 = (f16*)d_ws;   // 4 x 128 x 128 f16 = 128KB
  float* d_x    = (float*)d_out;
  float* d_attn = d_x + (size_t)16 * 16 * 16 * 64 * 128;  // 33,554,432
  wcvt_kernel<<<64, 256, 0, stream>>>(Wq, Wk, Wv, Wp, W16);
  fpca_kernel<<<4096, 512, 0, stream>>>(q, k, v, pos, W16, bq, bv, bp, ls,
                                        d_x, d_attn);
}